// Round 5
// baseline (295.953 us; speedup 1.0000x reference)
//
#include <hip/hip_runtime.h>
#include <math.h>

#define ND 11      // node feature dim
#define ED 5       // edge feature dim
#define NL 3       // NNConv layers
#define NSTEPS 3   // Set2Set steps
#define BN_EPS 1e-5f
#define KSPLIT 4   // k-slice ranges of 17 (65 total incl. bias slice)

typedef _Float16 half8 __attribute__((ext_vector_type(8)));
typedef float f32x4 __attribute__((ext_vector_type(4)));

__device__ __forceinline__ float sigm(float x) { return 1.0f / (1.0f + expf(-x)); }

__device__ __forceinline__ half8 to_h8(float4 a, float4 b) {
  half8 r;
  r[0] = (_Float16)a.x; r[1] = (_Float16)a.y; r[2] = (_Float16)a.z; r[3] = (_Float16)a.w;
  r[4] = (_Float16)b.x; r[5] = (_Float16)b.y; r[6] = (_Float16)b.z; r[7] = (_Float16)b.w;
  return r;
}

// ---------------- zero the small accumulator region ----------------
__global__ void k_zero(float* __restrict__ p, long Z) {
  long i4 = (long)(blockIdx.x * blockDim.x + threadIdx.x) * 4;
  long stride = (long)gridDim.x * blockDim.x * 4;
  for (; i4 + 3 < Z; i4 += stride) *(float4*)(p + i4) = make_float4(0.f, 0.f, 0.f, 0.f);
  if (i4 < Z) for (; i4 < Z; ++i4) p[i4] = 0.f;  // tail
}

// ---------------- in-degree ----------------
__global__ void k_deg(const int* __restrict__ dst, float* __restrict__ deg, int E) {
  int e = blockIdx.x * blockDim.x + threadIdx.x;
  if (e < E) atomicAdd(&deg[dst[e]], 1.0f);
}

// ---------------- node encoder: h = relu(x @ W_enc + b) ----------------
__global__ void k_enc(const float* __restrict__ x, const float* __restrict__ W,
                      const float* __restrict__ bias, float* __restrict__ h, int N) {
  int idx = blockIdx.x * blockDim.x + threadIdx.x;
  if (idx >= N * 64) return;
  int n = idx >> 6, j = idx & 63;
  float acc = bias[j];
#pragma unroll
  for (int i = 0; i < ND; ++i) acc = fmaf(x[n * ND + i], W[i * 64 + j], acc);
  h[idx] = fmaxf(acc, 0.0f);
}

// ---------------- single-block prefix scan of deg -> dptr / cursor ----------------
__global__ __launch_bounds__(256) void k_scan(const float* __restrict__ deg,
                                              int* __restrict__ dptr,
                                              int* __restrict__ cursor, int N) {
  __shared__ int wsum[4];
  __shared__ int s_carry;
  const int tid = threadIdx.x, lane = tid & 63, w = tid >> 6;
  if (tid == 0) s_carry = 0;
  __syncthreads();
  for (int base = 0; base < N; base += 1024) {
    int n0 = base + tid * 4;
    int v[4];
    int s = 0;
#pragma unroll
    for (int i = 0; i < 4; ++i) { v[i] = (n0 + i < N) ? (int)deg[n0 + i] : 0; s += v[i]; }
    int sc = s;  // inclusive wave scan
#pragma unroll
    for (int off = 1; off < 64; off <<= 1) {
      int t = __shfl_up(sc, off);
      if (lane >= off) sc += t;
    }
    if (lane == 63) wsum[w] = sc;
    __syncthreads();
    int wpre = 0;
    for (int ww = 0; ww < w; ++ww) wpre += wsum[ww];
    int excl = s_carry + wpre + sc - s;
#pragma unroll
    for (int i = 0; i < 4; ++i) {
      if (n0 + i < N) { dptr[n0 + i] = excl; cursor[n0 + i] = excl; }
      excl += v[i];
    }
    __syncthreads();
    if (tid == 255) s_carry += wsum[0] + wsum[1] + wsum[2] + wsum[3];
    __syncthreads();
  }
  if (threadIdx.x == 0) dptr[N] = s_carry;
}

// ---------------- scatter: dst-sorted edge permutation + permuted src ----------------
__global__ void k_fill(const int* __restrict__ dst, const int* __restrict__ src,
                       int* __restrict__ cursor, int* __restrict__ perm,
                       int* __restrict__ srcP, int E) {
  int e = blockIdx.x * blockDim.x + threadIdx.x;
  if (e < E) {
    int slot = atomicAdd(&cursor[dst[e]], 1);
    perm[slot] = e;
    srcP[slot] = src[e];
  }
}

// ---------------- edge MLP layer1 (all 3 layers), PERMUTED slot order ----------------
// e1T layout: [l][k][slot]
__global__ __launch_bounds__(256) void k_prep(
    const float* __restrict__ ea, const int* __restrict__ perm,
    const float* __restrict__ eW1, const float* __restrict__ eb1,
    float* __restrict__ e1T, int E) {
  const int l = blockIdx.y;
  __shared__ float w1[ED * 64];
  __shared__ float b1[64];
  int tid = threadIdx.x;
  for (int i = tid; i < ED * 64; i += 256) w1[i] = eW1[(size_t)l * ED * 64 + i];
  if (tid < 64) b1[tid] = eb1[l * 64 + tid];
  __syncthreads();
  int s = blockIdx.x * 256 + tid;
  if (s >= E) return;
  int e = perm[s];
  float a[ED];
#pragma unroll
  for (int i = 0; i < ED; ++i) a[i] = ea[(size_t)e * ED + i];
  float* outb = e1T + (size_t)l * 64 * E + s;
#pragma unroll 8
  for (int k = 0; k < 64; ++k) {
    float acc = b1[k];
#pragma unroll
    for (int i = 0; i < ED; ++i) acc = fmaf(a[i], w1[i * 64 + k], acc);
    outb[(size_t)k * E] = fmaxf(acc, 0.0f);
  }
}

// ---------------- pack eW2 (+eb2 as slice 64) into MFMA-B frag-ready f16, all layers ----
__global__ void k_pack3(const float* __restrict__ w2, const float* __restrict__ b2,
                        _Float16* __restrict__ w2P) {
  int idx = blockIdx.x * blockDim.x + threadIdx.x;
  if (idx >= 65 * 8 * 64) return;
  int lay = blockIdx.y;
  int l = idx & 63;
  int f = (idx >> 6) & 7;
  int s = idx >> 9;
  int nf = f >> 1, kf = f & 1;
  const float* srow = (s < 64) ? (w2 + (size_t)lay * 64 * 4096 + (size_t)s * 4096)
                               : (b2 + (size_t)lay * 4096);
  int o = nf * 16 + (l & 15);
  int hb = kf * 32 + (l >> 4) * 8;
  half8 v;
#pragma unroll
  for (int j = 0; j < 8; ++j) v[j] = (_Float16)srow[(hb + j) * 64 + o];
  *(half8*)(w2P + ((size_t)lay * 65 * 8 * 64 + idx) * 8) = v;
}

// ---------------- transpose LSTM weights for coalesced gate loop ----------------
__global__ void k_packW(const float* __restrict__ Wih, const float* __restrict__ Whh,
                        const float* __restrict__ bih, const float* __restrict__ bhh,
                        float* __restrict__ WihT, float* __restrict__ WhhT,
                        float* __restrict__ gbias) {
  int idx = blockIdx.x * blockDim.x + threadIdx.x;
  if (idx < 128 * 256) {
    int i = idx >> 8, g = idx & 255;
    WihT[i * 256 + g] = Wih[g * 128 + i];
  } else if (idx < 192 * 256) {
    int j = idx - 128 * 256;
    int i = j >> 8, g = j & 255;
    WhhT[i * 256 + g] = Whh[g * 64 + i];
  } else if (idx < 192 * 256 + 256) {
    int g = idx - 192 * 256;
    gbias[g] = bih[g] + bhh[g];
  }
}

__device__ __forceinline__ float e1_scalar(const float* __restrict__ e1T, int k, int s, int E) {
  if (k >= 64) return 1.0f;  // bias slice: coefficient 1
  return (s < E) ? e1T[(size_t)k * E + s] : 0.0f;
}

// ---------------- NNConv message, NO atomics, permuted edge order ----------------
// block = 4 waves over ONE 64-slot tile; wave wid computes output quadrant nf=wid.
// gridDim.y = KSPLIT ranges of 17 k-slices; partials to msgS[ks][Epad][64] (plain stores).
__global__ __launch_bounds__(256) void k_msg(
    const float* __restrict__ e1T, const float* __restrict__ h,
    const int* __restrict__ srcP, const _Float16* __restrict__ w2P,
    float* __restrict__ msgS, int E, int Epad) {
  const int tid = threadIdx.x;
  const int wid = tid >> 6, l = tid & 63;
  const int lo = l & 15, lg = l >> 4;
  const int e0 = blockIdx.x * 64;
  const int ks = blockIdx.y;
  const int kbeg = ks * 17;
  const int kend = (kbeg + 17 < 65) ? (kbeg + 17) : 65;

  half8 hsf[4][2];
  int eIdx[4];
#pragma unroll
  for (int m = 0; m < 4; ++m) {
    int e = e0 + m * 16 + lo;
    eIdx[m] = e;
    if (e < E) {
      const float* hr = h + (size_t)srcP[e] * 64 + lg * 8;
      float4 a0 = *(const float4*)(hr);
      float4 a1 = *(const float4*)(hr + 4);
      float4 b0 = *(const float4*)(hr + 32);
      float4 b1 = *(const float4*)(hr + 36);
      hsf[m][0] = to_h8(a0, a1);
      hsf[m][1] = to_h8(b0, b1);
    } else {
      half8 z = {0, 0, 0, 0, 0, 0, 0, 0};
      hsf[m][0] = z;
      hsf[m][1] = z;
    }
  }

  f32x4 acc[4] = {};
  const half8* wp = (const half8*)w2P;  // [65][8][64] half8 units

  half8 Bc[2];
#pragma unroll
  for (int kf = 0; kf < 2; ++kf) Bc[kf] = wp[((size_t)kbeg * 8 + wid * 2 + kf) * 64 + l];
  float sc[4];
#pragma unroll
  for (int m = 0; m < 4; ++m) sc[m] = e1_scalar(e1T, kbeg, eIdx[m], E);

  for (int k = kbeg; k < kend; ++k) {
    half8 Bn[2];
    float sn[4];
    const bool more = (k + 1 < kend);
    if (more) {  // prefetch next slice
#pragma unroll
      for (int kf = 0; kf < 2; ++kf) Bn[kf] = wp[((size_t)(k + 1) * 8 + wid * 2 + kf) * 64 + l];
#pragma unroll
      for (int m = 0; m < 4; ++m) sn[m] = e1_scalar(e1T, k + 1, eIdx[m], E);
    }
#pragma unroll
    for (int m = 0; m < 4; ++m) {
      const _Float16 s16 = (_Float16)sc[m];
      half8 A0 = hsf[m][0] * s16;  // v_pk_mul_f16: fold e1[e,k] into A rows
      half8 A1 = hsf[m][1] * s16;
      acc[m] = __builtin_amdgcn_mfma_f32_16x16x32_f16(A0, Bc[0], acc[m], 0, 0, 0);
      acc[m] = __builtin_amdgcn_mfma_f32_16x16x32_f16(A1, Bc[1], acc[m], 0, 0, 0);
    }
    if (more) {
      Bc[0] = Bn[0]; Bc[1] = Bn[1];
#pragma unroll
      for (int m = 0; m < 4; ++m) sc[m] = sn[m];
    }
  }

  // store partials: D layout col = l&15, row = (l>>4)*4 + reg
  float* sbase = msgS + (size_t)ks * Epad * 64 + wid * 16 + lo;
#pragma unroll
  for (int m = 0; m < 4; ++m) {
#pragma unroll
    for (int r = 0; r < 4; ++r) {
      int e = e0 + m * 16 + lg * 4 + r;
      if (e < E) sbase[(size_t)e * 64] = acc[m][r];
    }
  }
}

// ---------------- hn = stream-gather(msgS)/deg + h@root + cbias ; BN stats ----------------
__global__ __launch_bounds__(256) void k_update(
    const float* __restrict__ msgS, const int* __restrict__ dptr,
    const float* __restrict__ deg,
    const float* __restrict__ h, const float* __restrict__ root,
    const float* __restrict__ cbias, float* __restrict__ hn,
    float* __restrict__ bnstats, int N, int E, int Epad) {
  __shared__ float hrow[16][64];
  __shared__ float red[2][256];
  const int tid = threadIdx.x, o = tid & 63, r = tid >> 6;
  const int nb = blockIdx.x * 16;
#pragma unroll
  for (int ii = 0; ii < 4; ++ii) {
    int n = nb + ii * 4 + r;
    hrow[ii * 4 + r][o] = (n < N) ? h[(size_t)n * 64 + o] : 0.0f;
  }
  __syncthreads();
  float acc[4] = {0.f, 0.f, 0.f, 0.f};
  for (int c = 0; c < 64; ++c) {
    float rv = root[c * 64 + o];
#pragma unroll
    for (int ii = 0; ii < 4; ++ii) acc[ii] = fmaf(hrow[ii * 4 + r][c], rv, acc[ii]);
  }
  float s = 0.f, ss = 0.f;
  const float cb = cbias[o];
#pragma unroll
  for (int ii = 0; ii < 4; ++ii) {
    int n = nb + ii * 4 + r;
    if (n < N) {
      int d0 = dptr[n], d1 = dptr[n + 1];
      d0 = (d0 < 0) ? 0 : d0;          // defensive clamps: garbage-proof profiling replays
      d1 = (d1 > E) ? E : d1;
      float g = 0.f;
      for (int j = d0; j < d1; ++j) {  // CONTIGUOUS slots (edges dst-sorted)
        const float* mrow = msgS + (size_t)j * 64 + o;
#pragma unroll
        for (int sp = 0; sp < KSPLIT; ++sp) g += mrow[(size_t)sp * Epad * 64];
      }
      float v = acc[ii] + cb + g / fmaxf(deg[n], 1.0f);
      hn[(size_t)n * 64 + o] = v;
      s += v;
      ss += v * v;
    }
  }
  red[0][tid] = s;
  red[1][tid] = ss;
  __syncthreads();
  if (r == 0) {
    float t0 = red[0][o] + red[0][64 + o] + red[0][128 + o] + red[0][192 + o];
    float t1 = red[1][o] + red[1][64 + o] + red[1][128 + o] + red[1][192 + o];
    atomicAdd(&bnstats[o], t0);
    atomicAdd(&bnstats[64 + o], t1);
  }
}

// ---------------- BN(train stats) + relu + residual, in place into h ----------------
__global__ void k_bn(const float* __restrict__ hn, const float* __restrict__ bnstats,
                     const float* __restrict__ gamma, const float* __restrict__ beta,
                     float* __restrict__ h, int N) {
  int idx = blockIdx.x * blockDim.x + threadIdx.x;
  if (idx >= N * 64) return;
  int o = idx & 63;
  float invN = 1.0f / (float)N;
  float mu = bnstats[o] * invN;
  float var = bnstats[64 + o] * invN - mu * mu;
  float y = (hn[idx] - mu) * rsqrtf(var + BN_EPS) * gamma[o] + beta[o];
  h[idx] += fmaxf(y, 0.0f);
}

// ---------------- graph row pointers from sorted batch ----------------
__global__ void k_ptr(const int* __restrict__ batch, int* __restrict__ ptr, int N, int B) {
  int n = blockIdx.x * blockDim.x + threadIdx.x;
  if (n >= N) return;
  int b = batch[n];
  int pb = (n == 0) ? -1 : batch[n - 1];
  for (int g = pb + 1; g <= b; ++g) ptr[g] = n;
  if (n == N - 1)
    for (int g = b + 1; g <= B; ++g) ptr[g] = N;
}

// ---------------- fused Set2Set step: LSTM + attention (+ head on final step) ----------
__global__ __launch_bounds__(256) void k_s2s(
    const float* __restrict__ h, const int* __restrict__ ptr,
    float* __restrict__ qstar, float* __restrict__ hl, float* __restrict__ cl,
    const float* __restrict__ WihT, const float* __restrict__ WhhT,
    const float* __restrict__ gbias,
    const float* __restrict__ hW1, const float* __restrict__ hb1,
    const float* __restrict__ hW2, const float* __restrict__ hb2,
    const float* __restrict__ hW3, const float* __restrict__ hb3,
    float* __restrict__ out, int final_step) {
  __shared__ float qs[128];
  __shared__ float hs[64];
  __shared__ float gates[256];
  __shared__ float qv[64];
  __shared__ float redM[4], redS[4];
  __shared__ float redR[4][64];
  __shared__ float qs2[128];
  __shared__ float z1[64], z2[32];
  const int b = blockIdx.x, tid = threadIdx.x;
  const int wid = tid >> 6, lane = tid & 63;

  // ---- LSTM (coalesced: transposed weights) ----
  if (tid < 128) qs[tid] = qstar[b * 128 + tid];
  if (tid < 64) hs[tid] = hl[b * 64 + tid];
  __syncthreads();
  float g = gbias[tid];
  for (int i = 0; i < 128; ++i) g = fmaf(qs[i], WihT[i * 256 + tid], g);
  for (int i = 0; i < 64; ++i) g = fmaf(hs[i], WhhT[i * 256 + tid], g);
  gates[tid] = g;
  __syncthreads();
  if (tid < 64) {
    float ig = sigm(gates[tid]);
    float fg = sigm(gates[64 + tid]);
    float gg = tanhf(gates[128 + tid]);
    float og = sigm(gates[192 + tid]);
    float c = fg * cl[b * 64 + tid] + ig * gg;
    cl[b * 64 + tid] = c;
    float hnew = og * tanhf(c);
    hl[b * 64 + tid] = hnew;
    qv[tid] = hnew;
  }
  __syncthreads();

  // ---- attention (4 waves over nodes) ----
  const int beg = ptr[b], end = ptr[b + 1];
  const float q = qv[lane];
  float mw = -INFINITY;
  for (int n = beg + wid; n < end; n += 4) {
    float p = h[(size_t)n * 64 + lane] * q;
#pragma unroll
    for (int s = 32; s; s >>= 1) p += __shfl_xor(p, s);
    mw = fmaxf(mw, p);
  }
  if (lane == 0) redM[wid] = mw;
  __syncthreads();
  const float m = fmaxf(fmaxf(redM[0], redM[1]), fmaxf(redM[2], redM[3]));
  float ssum = 0.f, racc = 0.f;
  for (int n = beg + wid; n < end; n += 4) {
    float hv = h[(size_t)n * 64 + lane];
    float p = hv * q;
#pragma unroll
    for (int s = 32; s; s >>= 1) p += __shfl_xor(p, s);
    float a = expf(p - m);
    ssum += a;
    racc = fmaf(a, hv, racc);
  }
  if (lane == 0) redS[wid] = ssum;
  redR[wid][lane] = racc;
  __syncthreads();
  if (tid < 64) {
    float rs = redR[0][tid] + redR[1][tid] + redR[2][tid] + redR[3][tid];
    float sd = redS[0] + redS[1] + redS[2] + redS[3];
    float rr = (end > beg) ? rs / sd : 0.0f;
    qstar[b * 128 + tid] = qv[tid];
    qstar[b * 128 + 64 + tid] = rr;
    qs2[tid] = qv[tid];
    qs2[64 + tid] = rr;
  }
  if (!final_step) return;
  __syncthreads();

  // ---- regression head ----
  if (tid < 64) {
    float a = hb1[tid];
    for (int i = 0; i < 128; ++i) a = fmaf(qs2[i], hW1[i * 64 + tid], a);
    z1[tid] = fmaxf(a, 0.0f);
  }
  __syncthreads();
  if (tid < 32) {
    float a2 = hb2[tid];
    for (int i = 0; i < 64; ++i) a2 = fmaf(z1[i], hW2[i * 32 + tid], a2);
    z2[tid] = fmaxf(a2, 0.0f);
  }
  __syncthreads();
  if (tid < 64) {
    float p = (tid < 32) ? z2[tid] * hW3[tid] : 0.0f;
#pragma unroll
    for (int s = 32; s; s >>= 1) p += __shfl_xor(p, s);
    if (tid == 0) out[b] = p + hb3[0];
  }
}

extern "C" void kernel_launch(void* const* d_in, const int* in_sizes, int n_in,
                              void* d_out, int out_size, void* d_ws, size_t ws_size,
                              hipStream_t stream) {
  const float* x = (const float*)d_in[0];
  const int* eidx = (const int*)d_in[1];
  const float* ea = (const float*)d_in[2];
  const int* batch = (const int*)d_in[3];
  const float* Wenc = (const float*)d_in[4];
  const float* benc = (const float*)d_in[5];
  const float* eW1 = (const float*)d_in[6];
  const float* eb1 = (const float*)d_in[7];
  const float* eW2 = (const float*)d_in[8];
  const float* eb2 = (const float*)d_in[9];
  const float* root = (const float*)d_in[10];
  const float* cbias = (const float*)d_in[11];
  const float* gamma = (const float*)d_in[12];
  const float* beta = (const float*)d_in[13];
  const float* Wih = (const float*)d_in[14];
  const float* Whh = (const float*)d_in[15];
  const float* bih = (const float*)d_in[16];
  const float* bhh = (const float*)d_in[17];
  const float* hW1 = (const float*)d_in[18];
  const float* hb1 = (const float*)d_in[19];
  const float* hW2 = (const float*)d_in[20];
  const float* hb2 = (const float*)d_in[21];
  const float* hW3 = (const float*)d_in[22];
  const float* hb3 = (const float*)d_in[23];

  const int N = in_sizes[0] / ND;
  const int E = in_sizes[1] / 2;
  const int B = out_size;
  const int* srcp = eidx;
  const int* dstp = eidx + E;
  const int Etiles = (E + 63) / 64;
  const int Epad = Etiles * 64;

  // ---- workspace layout: [zeroed region | rest] ----
  float* ws = (float*)d_ws;
  float* deg = ws;                                     // N
  float* bnstats = deg + N;                            // 3 * 128
  float* qstar = bnstats + 384;                        // B*128
  float* hl = qstar + (size_t)B * 128;                 // B*64
  float* cl = hl + (size_t)B * 64;                     // B*64
  const long Z = (long)(cl + (size_t)B * 64 - ws);     // zeroed float count
  float* h = cl + (size_t)B * 64;                      // N*64
  float* hn = h + (size_t)N * 64;                      // N*64
  float* e1T = hn + (size_t)N * 64;                    // 3 * 64*E  (slot order)
  _Float16* w2P = (_Float16*)(e1T + (size_t)3 * 64 * E);  // 3 * 65*8*64*8 f16
  float* msgS = (float*)(w2P + (size_t)3 * 65 * 8 * 64 * 8);  // KSPLIT * Epad * 64
  float* WihT = msgS + (size_t)KSPLIT * Epad * 64;     // 128*256
  float* WhhT = WihT + 128 * 256;                      // 64*256
  float* gbias = WhhT + 64 * 256;                      // 256
  int* dptr = (int*)(gbias + 256);                     // N+1
  int* cursor = dptr + N + 1;                          // N
  int* perm = cursor + N;                              // E
  int* srcP = perm + E;                                // E
  int* ptr = srcP + E;                                 // B+1

  k_zero<<<256, 256, 0, stream>>>(ws, Z);
  k_deg<<<(E + 255) / 256, 256, 0, stream>>>(dstp, deg, E);
  k_enc<<<(N * 64 + 255) / 256, 256, 0, stream>>>(x, Wenc, benc, h, N);
  k_ptr<<<(N + 255) / 256, 256, 0, stream>>>(batch, ptr, N, B);
  k_scan<<<1, 256, 0, stream>>>(deg, dptr, cursor, N);
  k_fill<<<(E + 255) / 256, 256, 0, stream>>>(dstp, srcp, cursor, perm, srcP, E);
  dim3 gp((E + 255) / 256, NL);
  k_prep<<<gp, 256, 0, stream>>>(ea, perm, eW1, eb1, e1T, E);
  dim3 gk((65 * 8 * 64 + 255) / 256, NL);
  k_pack3<<<gk, 256, 0, stream>>>(eW2, eb2, w2P);
  k_packW<<<(192 * 256 + 256 + 255) / 256, 256, 0, stream>>>(Wih, Whh, bih, bhh,
                                                             WihT, WhhT, gbias);

  for (int l = 0; l < NL; ++l) {
    float* bn_l = bnstats + l * 128;
    const float* e1_l = e1T + (size_t)l * 64 * E;
    const _Float16* w2_l = w2P + (size_t)l * 65 * 8 * 64 * 8;
    dim3 gm(Etiles, KSPLIT);
    k_msg<<<gm, 256, 0, stream>>>(e1_l, h, srcP, w2_l, msgS, E, Epad);
    k_update<<<(N + 15) / 16, 256, 0, stream>>>(msgS, dptr, deg, h,
                                                root + l * 64 * 64, cbias + l * 64,
                                                hn, bn_l, N, E, Epad);
    k_bn<<<(N * 64 + 255) / 256, 256, 0, stream>>>(hn, bn_l, gamma + l * 64,
                                                   beta + l * 64, h, N);
  }

  for (int s = 0; s < NSTEPS; ++s) {
    k_s2s<<<B, 256, 0, stream>>>(h, ptr, qstar, hl, cl, WihT, WhhT, gbias,
                                 hW1, hb1, hW2, hb2, hW3, hb3, (float*)d_out,
                                 (s == NSTEPS - 1) ? 1 : 0);
  }
}

// Round 6
// 241.150 us; speedup vs baseline: 1.2273x; 1.2273x over previous
//
#include <hip/hip_runtime.h>
#include <math.h>

#define ND 11      // node feature dim
#define ED 5       // edge feature dim
#define NL 3       // NNConv layers
#define NSTEPS 3   // Set2Set steps
#define BN_EPS 1e-5f
#define KSPLIT 4   // k-slice ranges of 17 (65 total incl. bias slice)
#define NSLAB 32   // bn-stat slabs (spread same-address atomics)

typedef _Float16 half8 __attribute__((ext_vector_type(8)));
typedef float f32x4 __attribute__((ext_vector_type(4)));

__device__ __forceinline__ float sigm(float x) { return 1.0f / (1.0f + expf(-x)); }

__device__ __forceinline__ half8 to_h8(float4 a, float4 b) {
  half8 r;
  r[0] = (_Float16)a.x; r[1] = (_Float16)a.y; r[2] = (_Float16)a.z; r[3] = (_Float16)a.w;
  r[4] = (_Float16)b.x; r[5] = (_Float16)b.y; r[6] = (_Float16)b.z; r[7] = (_Float16)b.w;
  return r;
}

// ---------------- zero the small accumulator region ----------------
__global__ void k_zero(float* __restrict__ p, long Z) {
  long i4 = (long)(blockIdx.x * blockDim.x + threadIdx.x) * 4;
  long stride = (long)gridDim.x * blockDim.x * 4;
  for (; i4 + 3 < Z; i4 += stride) *(float4*)(p + i4) = make_float4(0.f, 0.f, 0.f, 0.f);
  if (i4 < Z) for (; i4 < Z; ++i4) p[i4] = 0.f;  // tail
}

// ---------------- fused setup: enc | deg | ptr | packW | pack3 (independent parts) ----
__global__ __launch_bounds__(256) void k_setup(
    const float* __restrict__ x, const float* __restrict__ Wenc,
    const float* __restrict__ benc, float* __restrict__ h, int N,
    const int* __restrict__ dst, float* __restrict__ deg, int E,
    const int* __restrict__ batch, int* __restrict__ ptr, int B,
    const float* __restrict__ Wih, const float* __restrict__ Whh,
    const float* __restrict__ bih, const float* __restrict__ bhh,
    float* __restrict__ WihT, float* __restrict__ WhhT, float* __restrict__ gbias,
    const float* __restrict__ w2, const float* __restrict__ b2,
    _Float16* __restrict__ w2P,
    int nbEnc, int nbDeg, int nbPtr, int nbPackW) {
  int bid = blockIdx.x;
  const int tid = threadIdx.x;
  if (bid < nbEnc) {  // node encoder: h = relu(x @ W_enc + b)
    int idx = bid * 256 + tid;
    if (idx < N * 64) {
      int n = idx >> 6, j = idx & 63;
      float acc = benc[j];
#pragma unroll
      for (int i = 0; i < ND; ++i) acc = fmaf(x[n * ND + i], Wenc[i * 64 + j], acc);
      h[idx] = fmaxf(acc, 0.0f);
    }
    return;
  }
  bid -= nbEnc;
  if (bid < nbDeg) {  // in-degree
    int e = bid * 256 + tid;
    if (e < E) atomicAdd(&deg[dst[e]], 1.0f);
    return;
  }
  bid -= nbDeg;
  if (bid < nbPtr) {  // graph row pointers from sorted batch
    int n = bid * 256 + tid;
    if (n < N) {
      int b = batch[n];
      int pb = (n == 0) ? -1 : batch[n - 1];
      for (int g = pb + 1; g <= b; ++g) ptr[g] = n;
      if (n == N - 1)
        for (int g = b + 1; g <= B; ++g) ptr[g] = N;
    }
    return;
  }
  bid -= nbPtr;
  if (bid < nbPackW) {  // transpose LSTM weights
    int idx = bid * 256 + tid;
    if (idx < 128 * 256) {
      int i = idx >> 8, g = idx & 255;
      WihT[i * 256 + g] = Wih[g * 128 + i];
    } else if (idx < 192 * 256) {
      int j = idx - 128 * 256;
      int i = j >> 8, g = j & 255;
      WhhT[i * 256 + g] = Whh[g * 64 + i];
    } else if (idx < 192 * 256 + 256) {
      int g = idx - 192 * 256;
      gbias[g] = bih[g] + bhh[g];
    }
    return;
  }
  bid -= nbPackW;
  {  // pack eW2 (+eb2 as slice 64) into MFMA-B frag layout, 130 blocks/layer
    int lay = bid / 130;
    int idx = (bid % 130) * 256 + tid;  // < 65*8*64 = 33280 exactly
    int l = idx & 63;
    int f = (idx >> 6) & 7;
    int s = idx >> 9;
    int nf = f >> 1, kf = f & 1;
    const float* srow = (s < 64) ? (w2 + (size_t)lay * 64 * 4096 + (size_t)s * 4096)
                                 : (b2 + (size_t)lay * 4096);
    int o = nf * 16 + (l & 15);
    int hb = kf * 32 + (l >> 4) * 8;
    half8 v;
#pragma unroll
    for (int j = 0; j < 8; ++j) v[j] = (_Float16)srow[(hb + j) * 64 + o];
    *(half8*)(w2P + ((size_t)lay * 65 * 8 * 64 + idx) * 8) = v;
  }
}

// ---------------- single-block prefix scan of deg -> dptr / cursor ----------------
__global__ __launch_bounds__(256) void k_scan(const float* __restrict__ deg,
                                              int* __restrict__ dptr,
                                              int* __restrict__ cursor, int N) {
  __shared__ int wsum[4];
  __shared__ int s_carry;
  const int tid = threadIdx.x, lane = tid & 63, w = tid >> 6;
  if (tid == 0) s_carry = 0;
  __syncthreads();
  for (int base = 0; base < N; base += 1024) {
    int n0 = base + tid * 4;
    int v[4];
    int s = 0;
#pragma unroll
    for (int i = 0; i < 4; ++i) { v[i] = (n0 + i < N) ? (int)deg[n0 + i] : 0; s += v[i]; }
    int sc = s;  // inclusive wave scan
#pragma unroll
    for (int off = 1; off < 64; off <<= 1) {
      int t = __shfl_up(sc, off);
      if (lane >= off) sc += t;
    }
    if (lane == 63) wsum[w] = sc;
    __syncthreads();
    int wpre = 0;
    for (int ww = 0; ww < w; ++ww) wpre += wsum[ww];
    int excl = s_carry + wpre + sc - s;
#pragma unroll
    for (int i = 0; i < 4; ++i) {
      if (n0 + i < N) { dptr[n0 + i] = excl; cursor[n0 + i] = excl; }
      excl += v[i];
    }
    __syncthreads();
    if (tid == 255) s_carry += wsum[0] + wsum[1] + wsum[2] + wsum[3];
    __syncthreads();
  }
  if (threadIdx.x == 0) dptr[N] = s_carry;
}

// ---------------- scatter: dst-sorted edge permutation + permuted src ----------------
__global__ void k_fill(const int* __restrict__ dst, const int* __restrict__ src,
                       int* __restrict__ cursor, int* __restrict__ perm,
                       int* __restrict__ srcP, int E) {
  int e = blockIdx.x * blockDim.x + threadIdx.x;
  if (e < E) {
    int slot = atomicAdd(&cursor[dst[e]], 1);
    perm[slot] = e;
    srcP[slot] = src[e];
  }
}

// ---------------- edge MLP layer1 (all 3 layers), PERMUTED slot order ----------------
// e1T layout: [l][k][slot]
__global__ __launch_bounds__(256) void k_prep(
    const float* __restrict__ ea, const int* __restrict__ perm,
    const float* __restrict__ eW1, const float* __restrict__ eb1,
    float* __restrict__ e1T, int E) {
  const int l = blockIdx.y;
  __shared__ float w1[ED * 64];
  __shared__ float b1[64];
  int tid = threadIdx.x;
  for (int i = tid; i < ED * 64; i += 256) w1[i] = eW1[(size_t)l * ED * 64 + i];
  if (tid < 64) b1[tid] = eb1[l * 64 + tid];
  __syncthreads();
  int s = blockIdx.x * 256 + tid;
  if (s >= E) return;
  int e = perm[s];
  float a[ED];
#pragma unroll
  for (int i = 0; i < ED; ++i) a[i] = ea[(size_t)e * ED + i];
  float* outb = e1T + (size_t)l * 64 * E + s;
#pragma unroll 8
  for (int k = 0; k < 64; ++k) {
    float acc = b1[k];
#pragma unroll
    for (int i = 0; i < ED; ++i) acc = fmaf(a[i], w1[i * 64 + k], acc);
    outb[(size_t)k * E] = fmaxf(acc, 0.0f);
  }
}

__device__ __forceinline__ float e1_scalar(const float* __restrict__ e1T, int k, int s, int E) {
  if (k >= 64) return 1.0f;  // bias slice: coefficient 1
  return (s < E) ? e1T[(size_t)k * E + s] : 0.0f;
}

// ---------------- NNConv message, NO atomics, permuted edge order ----------------
__global__ __launch_bounds__(256) void k_msg(
    const float* __restrict__ e1T, const float* __restrict__ h,
    const int* __restrict__ srcP, const _Float16* __restrict__ w2P,
    float* __restrict__ msgS, int E, int Epad) {
  const int tid = threadIdx.x;
  const int wid = tid >> 6, l = tid & 63;
  const int lo = l & 15, lg = l >> 4;
  const int e0 = blockIdx.x * 64;
  const int ks = blockIdx.y;
  const int kbeg = ks * 17;
  const int kend = (kbeg + 17 < 65) ? (kbeg + 17) : 65;

  half8 hsf[4][2];
  int eIdx[4];
#pragma unroll
  for (int m = 0; m < 4; ++m) {
    int e = e0 + m * 16 + lo;
    eIdx[m] = e;
    if (e < E) {
      const float* hr = h + (size_t)srcP[e] * 64 + lg * 8;
      float4 a0 = *(const float4*)(hr);
      float4 a1 = *(const float4*)(hr + 4);
      float4 b0 = *(const float4*)(hr + 32);
      float4 b1 = *(const float4*)(hr + 36);
      hsf[m][0] = to_h8(a0, a1);
      hsf[m][1] = to_h8(b0, b1);
    } else {
      half8 z = {0, 0, 0, 0, 0, 0, 0, 0};
      hsf[m][0] = z;
      hsf[m][1] = z;
    }
  }

  f32x4 acc[4] = {};
  const half8* wp = (const half8*)w2P;  // [65][8][64] half8 units

  half8 Bc[2];
#pragma unroll
  for (int kf = 0; kf < 2; ++kf) Bc[kf] = wp[((size_t)kbeg * 8 + wid * 2 + kf) * 64 + l];
  float sc[4];
#pragma unroll
  for (int m = 0; m < 4; ++m) sc[m] = e1_scalar(e1T, kbeg, eIdx[m], E);

  for (int k = kbeg; k < kend; ++k) {
    half8 Bn[2];
    float sn[4];
    const bool more = (k + 1 < kend);
    if (more) {  // prefetch next slice
#pragma unroll
      for (int kf = 0; kf < 2; ++kf) Bn[kf] = wp[((size_t)(k + 1) * 8 + wid * 2 + kf) * 64 + l];
#pragma unroll
      for (int m = 0; m < 4; ++m) sn[m] = e1_scalar(e1T, k + 1, eIdx[m], E);
    }
#pragma unroll
    for (int m = 0; m < 4; ++m) {
      const _Float16 s16 = (_Float16)sc[m];
      half8 A0 = hsf[m][0] * s16;  // fold e1[e,k] into A rows
      half8 A1 = hsf[m][1] * s16;
      acc[m] = __builtin_amdgcn_mfma_f32_16x16x32_f16(A0, Bc[0], acc[m], 0, 0, 0);
      acc[m] = __builtin_amdgcn_mfma_f32_16x16x32_f16(A1, Bc[1], acc[m], 0, 0, 0);
    }
    if (more) {
      Bc[0] = Bn[0]; Bc[1] = Bn[1];
#pragma unroll
      for (int m = 0; m < 4; ++m) sc[m] = sn[m];
    }
  }

  // store partials: D layout col = l&15, row = (l>>4)*4 + reg
  float* sbase = msgS + (size_t)ks * Epad * 64 + wid * 16 + lo;
#pragma unroll
  for (int m = 0; m < 4; ++m) {
#pragma unroll
    for (int r = 0; r < 4; ++r) {
      int e = e0 + m * 16 + lg * 4 + r;
      if (e < E) sbase[(size_t)e * 64] = acc[m][r];
    }
  }
}

// ---------------- hn = stream-gather(msgS)/deg + h@root + cbias ; BN stats to slab ----
__global__ __launch_bounds__(256) void k_update(
    const float* __restrict__ msgS, const int* __restrict__ dptr,
    const float* __restrict__ deg,
    const float* __restrict__ h, const float* __restrict__ root,
    const float* __restrict__ cbias, float* __restrict__ hn,
    float* __restrict__ slab, int N, int E, int Epad) {
  __shared__ float hrow[16][64];
  __shared__ float red[2][256];
  const int tid = threadIdx.x, o = tid & 63, r = tid >> 6;
  const int nb = blockIdx.x * 16;
#pragma unroll
  for (int ii = 0; ii < 4; ++ii) {
    int n = nb + ii * 4 + r;
    hrow[ii * 4 + r][o] = (n < N) ? h[(size_t)n * 64 + o] : 0.0f;
  }
  __syncthreads();
  float acc[4] = {0.f, 0.f, 0.f, 0.f};
  for (int c = 0; c < 64; ++c) {
    float rv = root[c * 64 + o];
#pragma unroll
    for (int ii = 0; ii < 4; ++ii) acc[ii] = fmaf(hrow[ii * 4 + r][c], rv, acc[ii]);
  }
  float s = 0.f, ss = 0.f;
  const float cb = cbias[o];
#pragma unroll
  for (int ii = 0; ii < 4; ++ii) {
    int n = nb + ii * 4 + r;
    if (n < N) {
      int d0 = dptr[n], d1 = dptr[n + 1];
      d0 = (d0 < 0) ? 0 : d0;          // defensive clamps vs poisoned replays
      d1 = (d1 > E) ? E : d1;
      float g = 0.f;
      int j = d0;
      for (; j + 2 <= d1; j += 2) {    // 2x unroll: 8 independent loads in flight
        const float* m0 = msgS + (size_t)j * 64 + o;
        float a0 = 0.f, a1 = 0.f;
#pragma unroll
        for (int sp = 0; sp < KSPLIT; ++sp) {
          a0 += m0[(size_t)sp * Epad * 64];
          a1 += m0[(size_t)sp * Epad * 64 + 64];
        }
        g += a0 + a1;
      }
      if (j < d1) {
        const float* m0 = msgS + (size_t)j * 64 + o;
#pragma unroll
        for (int sp = 0; sp < KSPLIT; ++sp) g += m0[(size_t)sp * Epad * 64];
      }
      float v = acc[ii] + cb + g / fmaxf(deg[n], 1.0f);
      hn[(size_t)n * 64 + o] = v;
      s += v;
      ss += v * v;
    }
  }
  red[0][tid] = s;
  red[1][tid] = ss;
  __syncthreads();
  if (r == 0) {
    float t0 = red[0][o] + red[0][64 + o] + red[0][128 + o] + red[0][192 + o];
    float t1 = red[1][o] + red[1][64 + o] + red[1][128 + o] + red[1][192 + o];
    float* sl = slab + (size_t)(blockIdx.x & (NSLAB - 1)) * 128;  // spread hot addresses
    atomicAdd(&sl[o], t0);
    atomicAdd(&sl[64 + o], t1);
  }
}

// ---------------- BN(train stats from slabs) + relu + residual, in place into h --------
__global__ __launch_bounds__(256) void k_bn(
    const float* __restrict__ hn, const float* __restrict__ slab,
    const float* __restrict__ gamma, const float* __restrict__ beta,
    float* __restrict__ h, int N) {
  __shared__ float stats[128];
  const int tid = threadIdx.x;
  if (tid < 128) {
    float s = 0.f;
#pragma unroll
    for (int sl = 0; sl < NSLAB; ++sl) s += slab[sl * 128 + tid];
    stats[tid] = s;
  }
  __syncthreads();
  int idx = blockIdx.x * 256 + tid;
  if (idx >= N * 64) return;
  int o = idx & 63;
  float invN = 1.0f / (float)N;
  float mu = stats[o] * invN;
  float var = stats[64 + o] * invN - mu * mu;
  float y = (hn[idx] - mu) * rsqrtf(var + BN_EPS) * gamma[o] + beta[o];
  h[idx] += fmaxf(y, 0.0f);
}

// ---------------- fused Set2Set step: LSTM + attention (+ head on final step) ----------
__global__ __launch_bounds__(256) void k_s2s(
    const float* __restrict__ h, const int* __restrict__ ptr,
    float* __restrict__ qstar, float* __restrict__ hl, float* __restrict__ cl,
    const float* __restrict__ WihT, const float* __restrict__ WhhT,
    const float* __restrict__ gbias,
    const float* __restrict__ hW1, const float* __restrict__ hb1,
    const float* __restrict__ hW2, const float* __restrict__ hb2,
    const float* __restrict__ hW3, const float* __restrict__ hb3,
    float* __restrict__ out, int final_step) {
  __shared__ float qs[128];
  __shared__ float hs[64];
  __shared__ float gates[256];
  __shared__ float qv[64];
  __shared__ float redM[4], redS[4];
  __shared__ float redR[4][64];
  __shared__ float qs2[128];
  __shared__ float z1[64], z2[32];
  const int b = blockIdx.x, tid = threadIdx.x;
  const int wid = tid >> 6, lane = tid & 63;

  // ---- LSTM (coalesced: transposed weights) ----
  if (tid < 128) qs[tid] = qstar[b * 128 + tid];
  if (tid < 64) hs[tid] = hl[b * 64 + tid];
  __syncthreads();
  float g = gbias[tid];
  for (int i = 0; i < 128; ++i) g = fmaf(qs[i], WihT[i * 256 + tid], g);
  for (int i = 0; i < 64; ++i) g = fmaf(hs[i], WhhT[i * 256 + tid], g);
  gates[tid] = g;
  __syncthreads();
  if (tid < 64) {
    float ig = sigm(gates[tid]);
    float fg = sigm(gates[64 + tid]);
    float gg = tanhf(gates[128 + tid]);
    float og = sigm(gates[192 + tid]);
    float c = fg * cl[b * 64 + tid] + ig * gg;
    cl[b * 64 + tid] = c;
    float hnew = og * tanhf(c);
    hl[b * 64 + tid] = hnew;
    qv[tid] = hnew;
  }
  __syncthreads();

  // ---- attention (4 waves over nodes) ----
  const int beg = ptr[b], end = ptr[b + 1];
  const float q = qv[lane];
  float mw = -INFINITY;
  for (int n = beg + wid; n < end; n += 4) {
    float p = h[(size_t)n * 64 + lane] * q;
#pragma unroll
    for (int s = 32; s; s >>= 1) p += __shfl_xor(p, s);
    mw = fmaxf(mw, p);
  }
  if (lane == 0) redM[wid] = mw;
  __syncthreads();
  const float m = fmaxf(fmaxf(redM[0], redM[1]), fmaxf(redM[2], redM[3]));
  float ssum = 0.f, racc = 0.f;
  for (int n = beg + wid; n < end; n += 4) {
    float hv = h[(size_t)n * 64 + lane];
    float p = hv * q;
#pragma unroll
    for (int s = 32; s; s >>= 1) p += __shfl_xor(p, s);
    float a = expf(p - m);
    ssum += a;
    racc = fmaf(a, hv, racc);
  }
  if (lane == 0) redS[wid] = ssum;
  redR[wid][lane] = racc;
  __syncthreads();
  if (tid < 64) {
    float rs = redR[0][tid] + redR[1][tid] + redR[2][tid] + redR[3][tid];
    float sd = redS[0] + redS[1] + redS[2] + redS[3];
    float rr = (end > beg) ? rs / sd : 0.0f;
    qstar[b * 128 + tid] = qv[tid];
    qstar[b * 128 + 64 + tid] = rr;
    qs2[tid] = qv[tid];
    qs2[64 + tid] = rr;
  }
  if (!final_step) return;
  __syncthreads();

  // ---- regression head ----
  if (tid < 64) {
    float a = hb1[tid];
    for (int i = 0; i < 128; ++i) a = fmaf(qs2[i], hW1[i * 64 + tid], a);
    z1[tid] = fmaxf(a, 0.0f);
  }
  __syncthreads();
  if (tid < 32) {
    float a2 = hb2[tid];
    for (int i = 0; i < 64; ++i) a2 = fmaf(z1[i], hW2[i * 32 + tid], a2);
    z2[tid] = fmaxf(a2, 0.0f);
  }
  __syncthreads();
  if (tid < 64) {
    float p = (tid < 32) ? z2[tid] * hW3[tid] : 0.0f;
#pragma unroll
    for (int s = 32; s; s >>= 1) p += __shfl_xor(p, s);
    if (tid == 0) out[b] = p + hb3[0];
  }
}

extern "C" void kernel_launch(void* const* d_in, const int* in_sizes, int n_in,
                              void* d_out, int out_size, void* d_ws, size_t ws_size,
                              hipStream_t stream) {
  const float* x = (const float*)d_in[0];
  const int* eidx = (const int*)d_in[1];
  const float* ea = (const float*)d_in[2];
  const int* batch = (const int*)d_in[3];
  const float* Wenc = (const float*)d_in[4];
  const float* benc = (const float*)d_in[5];
  const float* eW1 = (const float*)d_in[6];
  const float* eb1 = (const float*)d_in[7];
  const float* eW2 = (const float*)d_in[8];
  const float* eb2 = (const float*)d_in[9];
  const float* root = (const float*)d_in[10];
  const float* cbias = (const float*)d_in[11];
  const float* gamma = (const float*)d_in[12];
  const float* beta = (const float*)d_in[13];
  const float* Wih = (const float*)d_in[14];
  const float* Whh = (const float*)d_in[15];
  const float* bih = (const float*)d_in[16];
  const float* bhh = (const float*)d_in[17];
  const float* hW1 = (const float*)d_in[18];
  const float* hb1 = (const float*)d_in[19];
  const float* hW2 = (const float*)d_in[20];
  const float* hb2 = (const float*)d_in[21];
  const float* hW3 = (const float*)d_in[22];
  const float* hb3 = (const float*)d_in[23];

  const int N = in_sizes[0] / ND;
  const int E = in_sizes[1] / 2;
  const int B = out_size;
  const int* srcp = eidx;
  const int* dstp = eidx + E;
  const int Etiles = (E + 63) / 64;
  const int Epad = Etiles * 64;

  // ---- workspace layout: [zeroed region | rest] ----
  float* ws = (float*)d_ws;
  float* deg = ws;                                     // N
  float* bnslab = deg + N;                             // NL * NSLAB * 128
  float* qstar = bnslab + NL * NSLAB * 128;            // B*128
  float* hl = qstar + (size_t)B * 128;                 // B*64
  float* cl = hl + (size_t)B * 64;                     // B*64
  const long Z = (long)(cl + (size_t)B * 64 - ws);     // zeroed float count
  float* h = cl + (size_t)B * 64;                      // N*64
  float* hn = h + (size_t)N * 64;                      // N*64
  float* e1T = hn + (size_t)N * 64;                    // 3 * 64*E  (slot order)
  _Float16* w2P = (_Float16*)(e1T + (size_t)3 * 64 * E);  // 3 * 65*8*64*8 f16
  float* msgS = (float*)(w2P + (size_t)3 * 65 * 8 * 64 * 8);  // KSPLIT * Epad * 64
  float* WihT = msgS + (size_t)KSPLIT * Epad * 64;     // 128*256
  float* WhhT = WihT + 128 * 256;                      // 64*256
  float* gbias = WhhT + 64 * 256;                      // 256
  int* dptr = (int*)(gbias + 256);                     // N+1
  int* cursor = dptr + N + 1;                          // N
  int* perm = cursor + N;                              // E
  int* srcP = perm + E;                                // E
  int* ptr = srcP + E;                                 // B+1

  const int nbEnc = (N * 64 + 255) / 256;
  const int nbDeg = (E + 255) / 256;
  const int nbPtr = (N + 255) / 256;
  const int nbPackW = (192 * 256 + 256 + 255) / 256;
  const int nbPack3 = 130 * NL;

  k_zero<<<256, 256, 0, stream>>>(ws, Z);
  k_setup<<<nbEnc + nbDeg + nbPtr + nbPackW + nbPack3, 256, 0, stream>>>(
      x, Wenc, benc, h, N, dstp, deg, E, batch, ptr, B,
      Wih, Whh, bih, bhh, WihT, WhhT, gbias, eW2, eb2, w2P,
      nbEnc, nbDeg, nbPtr, nbPackW);
  k_scan<<<1, 256, 0, stream>>>(deg, dptr, cursor, N);
  k_fill<<<(E + 255) / 256, 256, 0, stream>>>(dstp, srcp, cursor, perm, srcP, E);
  dim3 gp((E + 255) / 256, NL);
  k_prep<<<gp, 256, 0, stream>>>(ea, perm, eW1, eb1, e1T, E);

  for (int l = 0; l < NL; ++l) {
    float* slab_l = bnslab + (size_t)l * NSLAB * 128;
    const float* e1_l = e1T + (size_t)l * 64 * E;
    const _Float16* w2_l = w2P + (size_t)l * 65 * 8 * 64 * 8;
    dim3 gm(Etiles, KSPLIT);
    k_msg<<<gm, 256, 0, stream>>>(e1_l, h, srcP, w2_l, msgS, E, Epad);
    k_update<<<(N + 15) / 16, 256, 0, stream>>>(msgS, dptr, deg, h,
                                                root + l * 64 * 64, cbias + l * 64,
                                                hn, slab_l, N, E, Epad);
    k_bn<<<(N * 64 + 255) / 256, 256, 0, stream>>>(hn, slab_l, gamma + l * 64,
                                                   beta + l * 64, h, N);
  }

  for (int s = 0; s < NSTEPS; ++s) {
    k_s2s<<<B, 256, 0, stream>>>(h, ptr, qstar, hl, cl, WihT, WhhT, gbias,
                                 hW1, hb1, hW2, hb2, hW3, hb3, (float*)d_out,
                                 (s == NSTEPS - 1) ? 1 : 0);
  }
}

// Round 7
// 227.583 us; speedup vs baseline: 1.3004x; 1.0596x over previous
//
#include <hip/hip_runtime.h>
#include <math.h>

#define ND 11      // node feature dim
#define ED 5       // edge feature dim
#define NL 3       // NNConv layers
#define NSTEPS 3   // Set2Set steps
#define BN_EPS 1e-5f
#define NSLAB 32   // bn-stat slabs (spread same-address atomics)

typedef _Float16 half8 __attribute__((ext_vector_type(8)));
typedef float f32x4 __attribute__((ext_vector_type(4)));

__device__ __forceinline__ float sigm(float x) { return 1.0f / (1.0f + expf(-x)); }

__device__ __forceinline__ half8 to_h8(float4 a, float4 b) {
  half8 r;
  r[0] = (_Float16)a.x; r[1] = (_Float16)a.y; r[2] = (_Float16)a.z; r[3] = (_Float16)a.w;
  r[4] = (_Float16)b.x; r[5] = (_Float16)b.y; r[6] = (_Float16)b.z; r[7] = (_Float16)b.w;
  return r;
}

// ---------------- zero the accumulator region (deg|agg|bnslab|qstar|hl|cl) ----------------
__global__ void k_zero(float* __restrict__ p, long Z) {
  long i4 = (long)(blockIdx.x * blockDim.x + threadIdx.x) * 4;
  long stride = (long)gridDim.x * blockDim.x * 4;
  for (; i4 + 3 < Z; i4 += stride) *(float4*)(p + i4) = make_float4(0.f, 0.f, 0.f, 0.f);
  if (i4 < Z) for (; i4 < Z; ++i4) p[i4] = 0.f;  // tail
}

// ---------------- fused setup: enc | deg | ptr | packW | pack3 (independent parts) ----
__global__ __launch_bounds__(256) void k_setup(
    const float* __restrict__ x, const float* __restrict__ Wenc,
    const float* __restrict__ benc, float* __restrict__ h, int N,
    const int* __restrict__ dst, float* __restrict__ deg, int E,
    const int* __restrict__ batch, int* __restrict__ ptr, int B,
    const float* __restrict__ Wih, const float* __restrict__ Whh,
    const float* __restrict__ bih, const float* __restrict__ bhh,
    float* __restrict__ WihT, float* __restrict__ WhhT, float* __restrict__ gbias,
    const float* __restrict__ w2, const float* __restrict__ b2,
    _Float16* __restrict__ w2P,
    int nbEnc, int nbDeg, int nbPtr, int nbPackW) {
  int bid = blockIdx.x;
  const int tid = threadIdx.x;
  if (bid < nbEnc) {  // node encoder: h = relu(x @ W_enc + b)
    int idx = bid * 256 + tid;
    if (idx < N * 64) {
      int n = idx >> 6, j = idx & 63;
      float acc = benc[j];
#pragma unroll
      for (int i = 0; i < ND; ++i) acc = fmaf(x[n * ND + i], Wenc[i * 64 + j], acc);
      h[idx] = fmaxf(acc, 0.0f);
    }
    return;
  }
  bid -= nbEnc;
  if (bid < nbDeg) {  // in-degree
    int e = bid * 256 + tid;
    if (e < E) atomicAdd(&deg[dst[e]], 1.0f);
    return;
  }
  bid -= nbDeg;
  if (bid < nbPtr) {  // graph row pointers from sorted batch
    int n = bid * 256 + tid;
    if (n < N) {
      int b = batch[n];
      int pb = (n == 0) ? -1 : batch[n - 1];
      for (int g = pb + 1; g <= b; ++g) ptr[g] = n;
      if (n == N - 1)
        for (int g = b + 1; g <= B; ++g) ptr[g] = N;
    }
    return;
  }
  bid -= nbPtr;
  if (bid < nbPackW) {  // transpose LSTM weights
    int idx = bid * 256 + tid;
    if (idx < 128 * 256) {
      int i = idx >> 8, g = idx & 255;
      WihT[i * 256 + g] = Wih[g * 128 + i];
    } else if (idx < 192 * 256) {
      int j = idx - 128 * 256;
      int i = j >> 8, g = j & 255;
      WhhT[i * 256 + g] = Whh[g * 64 + i];
    } else if (idx < 192 * 256 + 256) {
      int g = idx - 192 * 256;
      gbias[g] = bih[g] + bhh[g];
    }
    return;
  }
  bid -= nbPackW;
  {  // pack eW2 (+eb2 as slice 64) into MFMA-B frag layout, 130 blocks/layer
    int lay = bid / 130;
    int idx = (bid % 130) * 256 + tid;  // < 65*8*64 = 33280 exactly
    int l = idx & 63;
    int f = (idx >> 6) & 7;
    int s = idx >> 9;
    int nf = f >> 1, kf = f & 1;
    const float* srow = (s < 64) ? (w2 + (size_t)lay * 64 * 4096 + (size_t)s * 4096)
                                 : (b2 + (size_t)lay * 4096);
    int o = nf * 16 + (l & 15);
    int hb = kf * 32 + (l >> 4) * 8;
    half8 v;
#pragma unroll
    for (int j = 0; j < 8; ++j) v[j] = (_Float16)srow[(hb + j) * 64 + o];
    *(half8*)(w2P + ((size_t)lay * 65 * 8 * 64 + idx) * 8) = v;
  }
}

// ---------------- single-block prefix scan of deg -> dptr / cursor ----------------
__global__ __launch_bounds__(256) void k_scan(const float* __restrict__ deg,
                                              int* __restrict__ dptr,
                                              int* __restrict__ cursor, int N) {
  __shared__ int wsum[4];
  __shared__ int s_carry;
  const int tid = threadIdx.x, lane = tid & 63, w = tid >> 6;
  if (tid == 0) s_carry = 0;
  __syncthreads();
  for (int base = 0; base < N; base += 1024) {
    int n0 = base + tid * 4;
    int v[4];
    int s = 0;
#pragma unroll
    for (int i = 0; i < 4; ++i) { v[i] = (n0 + i < N) ? (int)deg[n0 + i] : 0; s += v[i]; }
    int sc = s;  // inclusive wave scan
#pragma unroll
    for (int off = 1; off < 64; off <<= 1) {
      int t = __shfl_up(sc, off);
      if (lane >= off) sc += t;
    }
    if (lane == 63) wsum[w] = sc;
    __syncthreads();
    int wpre = 0;
    for (int ww = 0; ww < w; ++ww) wpre += wsum[ww];
    int excl = s_carry + wpre + sc - s;
#pragma unroll
    for (int i = 0; i < 4; ++i) {
      if (n0 + i < N) { dptr[n0 + i] = excl; cursor[n0 + i] = excl; }
      excl += v[i];
    }
    __syncthreads();
    if (tid == 255) s_carry += wsum[0] + wsum[1] + wsum[2] + wsum[3];
    __syncthreads();
  }
  if (threadIdx.x == 0) dptr[N] = s_carry;
}

// ---------------- scatter: dst-sorted edge permutation + permuted src/dst ----------------
__global__ void k_fill(const int* __restrict__ dst, const int* __restrict__ src,
                       int* __restrict__ cursor, int* __restrict__ perm,
                       int* __restrict__ srcP, int* __restrict__ dstP, int E) {
  int e = blockIdx.x * blockDim.x + threadIdx.x;
  if (e < E) {
    int d = dst[e];
    int slot = atomicAdd(&cursor[d], 1);
    perm[slot] = e;
    srcP[slot] = src[e];
    dstP[slot] = d;
  }
}

// ---------------- FUSED NNConv message (MFMA) + per-node aggregation ----------------
// One block = one 64-slot tile, 8 waves: half = k-range {0..32 | 33..64}, quad = 16-feat column.
// e1 computed on the fly in LDS (no e1T array); per-node sums from LDS tile; plain stores for
// interior nodes, atomicAdd only for tile-spanning (boundary) nodes. agg must be pre-zeroed.
__global__ __launch_bounds__(512, 4) void k_msgagg(
    const float* __restrict__ ea, const int* __restrict__ perm,
    const float* __restrict__ eW1l, const float* __restrict__ eb1l,
    const float* __restrict__ h, const int* __restrict__ srcP,
    const int* __restrict__ dstP, const int* __restrict__ dptr,
    const _Float16* __restrict__ w2P, float* __restrict__ agg, int E) {
  __shared__ float e1t[65][64];
  __shared__ float tileH[2][64][66];
  __shared__ float eat[64][ED];
  __shared__ float w1s[ED * 64];
  __shared__ float b1s[64];

  const int tid = threadIdx.x;
  const int wid = tid >> 6, l = tid & 63;
  const int half = wid >> 2, quad = wid & 3;
  const int lo = l & 15, lg = l >> 4;
  const int e0 = blockIdx.x * 64;

  // ---- stage w1/b1 and gathered ea rows ----
  if (tid < ED * 64) w1s[tid] = eW1l[tid];
  else if (tid < ED * 64 + 64) b1s[tid - ED * 64] = eb1l[tid - ED * 64];
  else if (tid >= 448) {  // 64 threads stage ea
    int s = e0 + (tid - 448);
    if (s < E) {
      int e = perm[s];
#pragma unroll
      for (int i = 0; i < ED; ++i) eat[tid - 448][i] = ea[(size_t)e * ED + i];
    } else {
#pragma unroll
      for (int i = 0; i < ED; ++i) eat[tid - 448][i] = 0.f;
    }
  }
  __syncthreads();

  // ---- edge MLP layer1 into LDS: e1t[k][edge], k=64 is the bias slice ----
  for (int idx = tid; idx < 65 * 64; idx += 512) {
    int el = idx & 63, k = idx >> 6;
    float v = 1.0f;
    if (k < 64) {
      v = b1s[k];
#pragma unroll
      for (int i = 0; i < ED; ++i) v = fmaf(eat[el][i], w1s[i * 64 + k], v);
      v = fmaxf(v, 0.f);
    }
    e1t[k][el] = v;
  }

  // ---- A-frags: h rows of the tile's 64 source nodes (OOR slots -> 0) ----
  half8 hsf[4][2];
#pragma unroll
  for (int m = 0; m < 4; ++m) {
    int s = e0 + m * 16 + lo;
    if (s < E) {
      const float* hr = h + (size_t)srcP[s] * 64 + lg * 8;
      float4 a0 = *(const float4*)(hr);
      float4 a1 = *(const float4*)(hr + 4);
      float4 b0 = *(const float4*)(hr + 32);
      float4 b1 = *(const float4*)(hr + 36);
      hsf[m][0] = to_h8(a0, a1);
      hsf[m][1] = to_h8(b0, b1);
    } else {
      half8 z = {0, 0, 0, 0, 0, 0, 0, 0};
      hsf[m][0] = z;
      hsf[m][1] = z;
    }
  }
  __syncthreads();  // e1t ready

  // ---- K-loop over this half's slices ----
  const int kbeg = half ? 33 : 0;
  const int kend = half ? 65 : 33;
  f32x4 acc[4] = {};
  const half8* wp = (const half8*)w2P;  // [65][8][64] half8 units
  half8 Bc[2];
#pragma unroll
  for (int kf = 0; kf < 2; ++kf) Bc[kf] = wp[((size_t)kbeg * 8 + quad * 2 + kf) * 64 + l];
  for (int k = kbeg; k < kend; ++k) {
    half8 Bn[2];
    const bool more = (k + 1 < kend);
    if (more) {
#pragma unroll
      for (int kf = 0; kf < 2; ++kf) Bn[kf] = wp[((size_t)(k + 1) * 8 + quad * 2 + kf) * 64 + l];
    }
#pragma unroll
    for (int m = 0; m < 4; ++m) {
      const _Float16 s16 = (_Float16)e1t[k][m * 16 + lo];
      half8 A0 = hsf[m][0] * s16;
      half8 A1 = hsf[m][1] * s16;
      acc[m] = __builtin_amdgcn_mfma_f32_16x16x32_f16(A0, Bc[0], acc[m], 0, 0, 0);
      acc[m] = __builtin_amdgcn_mfma_f32_16x16x32_f16(A1, Bc[1], acc[m], 0, 0, 0);
    }
    if (more) { Bc[0] = Bn[0]; Bc[1] = Bn[1]; }
  }

  // ---- store msg quadrant to LDS (D layout: col=l&15, row=(l>>4)*4+reg) ----
#pragma unroll
  for (int m = 0; m < 4; ++m)
#pragma unroll
    for (int r = 0; r < 4; ++r)
      tileH[half][m * 16 + lg * 4 + r][quad * 16 + lo] = acc[m][r];
  __syncthreads();

  // ---- per-node aggregation from LDS ----
  const int o = tid & 63, r8 = tid >> 6;
  const int lastSlot = (e0 + 63 < E) ? (e0 + 63) : (E - 1);
  const int nLo = dstP[e0], nHi = dstP[lastSlot];
  for (int nn = nLo + r8; nn <= nHi; nn += 8) {
    int d0 = dptr[nn], d1 = dptr[nn + 1];
    int j0 = (d0 > e0) ? d0 : e0;
    int j1 = (d1 < e0 + 64) ? d1 : (e0 + 64);
    float sum = 0.f;
    for (int j = j0; j < j1; ++j) sum += tileH[0][j - e0][o] + tileH[1][j - e0][o];
    float* dp = agg + (size_t)nn * 64 + o;
    if (d0 < e0 || d1 > e0 + 64) atomicAdd(dp, sum);  // tile-spanning node
    else *dp = sum;                                    // fully-owned node
  }
}

// ---------------- hn = agg/deg + h@root + cbias ; BN stats to slab ----------------
__global__ __launch_bounds__(256) void k_update(
    const float* __restrict__ agg, const float* __restrict__ deg,
    const float* __restrict__ h, const float* __restrict__ root,
    const float* __restrict__ cbias, float* __restrict__ hn,
    float* __restrict__ slab, int N) {
  __shared__ float hrow[16][64];
  __shared__ float red[2][256];
  const int tid = threadIdx.x, o = tid & 63, r = tid >> 6;
  const int nb = blockIdx.x * 16;
#pragma unroll
  for (int ii = 0; ii < 4; ++ii) {
    int n = nb + ii * 4 + r;
    hrow[ii * 4 + r][o] = (n < N) ? h[(size_t)n * 64 + o] : 0.0f;
  }
  __syncthreads();
  float acc[4] = {0.f, 0.f, 0.f, 0.f};
  for (int c = 0; c < 64; ++c) {
    float rv = root[c * 64 + o];
#pragma unroll
    for (int ii = 0; ii < 4; ++ii) acc[ii] = fmaf(hrow[ii * 4 + r][c], rv, acc[ii]);
  }
  float s = 0.f, ss = 0.f;
  const float cb = cbias[o];
#pragma unroll
  for (int ii = 0; ii < 4; ++ii) {
    int n = nb + ii * 4 + r;
    if (n < N) {
      float v = acc[ii] + cb + agg[(size_t)n * 64 + o] / fmaxf(deg[n], 1.0f);
      hn[(size_t)n * 64 + o] = v;
      s += v;
      ss += v * v;
    }
  }
  red[0][tid] = s;
  red[1][tid] = ss;
  __syncthreads();
  if (r == 0) {
    float t0 = red[0][o] + red[0][64 + o] + red[0][128 + o] + red[0][192 + o];
    float t1 = red[1][o] + red[1][64 + o] + red[1][128 + o] + red[1][192 + o];
    float* sl = slab + (size_t)(blockIdx.x & (NSLAB - 1)) * 128;
    atomicAdd(&sl[o], t0);
    atomicAdd(&sl[64 + o], t1);
  }
}

// ---------------- BN + relu + residual into h ; re-zero agg for next layer ----------
__global__ __launch_bounds__(256) void k_bn(
    const float* __restrict__ hn, const float* __restrict__ slab,
    const float* __restrict__ gamma, const float* __restrict__ beta,
    float* __restrict__ h, float* __restrict__ agg, int N) {
  __shared__ float stats[128];
  const int tid = threadIdx.x;
  if (tid < 128) {
    float s = 0.f;
#pragma unroll
    for (int sl = 0; sl < NSLAB; ++sl) s += slab[sl * 128 + tid];
    stats[tid] = s;
  }
  __syncthreads();
  int idx = blockIdx.x * 256 + tid;
  if (idx >= N * 64) return;
  int o = idx & 63;
  float invN = 1.0f / (float)N;
  float mu = stats[o] * invN;
  float var = stats[64 + o] * invN - mu * mu;
  float y = (hn[idx] - mu) * rsqrtf(var + BN_EPS) * gamma[o] + beta[o];
  h[idx] += fmaxf(y, 0.0f);
  agg[idx] = 0.f;  // reset boundary-atomic bases for next layer
}

// ---------------- fused Set2Set step: LSTM + attention (+ head on final step) ----------
__global__ __launch_bounds__(256) void k_s2s(
    const float* __restrict__ h, const int* __restrict__ ptr,
    float* __restrict__ qstar, float* __restrict__ hl, float* __restrict__ cl,
    const float* __restrict__ WihT, const float* __restrict__ WhhT,
    const float* __restrict__ gbias,
    const float* __restrict__ hW1, const float* __restrict__ hb1,
    const float* __restrict__ hW2, const float* __restrict__ hb2,
    const float* __restrict__ hW3, const float* __restrict__ hb3,
    float* __restrict__ out, int final_step) {
  __shared__ float qs[128];
  __shared__ float hs[64];
  __shared__ float gates[256];
  __shared__ float qv[64];
  __shared__ float redM[4], redS[4];
  __shared__ float redR[4][64];
  __shared__ float qs2[128];
  __shared__ float z1[64], z2[32];
  const int b = blockIdx.x, tid = threadIdx.x;
  const int wid = tid >> 6, lane = tid & 63;

  // ---- LSTM (coalesced: transposed weights) ----
  if (tid < 128) qs[tid] = qstar[b * 128 + tid];
  if (tid < 64) hs[tid] = hl[b * 64 + tid];
  __syncthreads();
  float g = gbias[tid];
  for (int i = 0; i < 128; ++i) g = fmaf(qs[i], WihT[i * 256 + tid], g);
  for (int i = 0; i < 64; ++i) g = fmaf(hs[i], WhhT[i * 256 + tid], g);
  gates[tid] = g;
  __syncthreads();
  if (tid < 64) {
    float ig = sigm(gates[tid]);
    float fg = sigm(gates[64 + tid]);
    float gg = tanhf(gates[128 + tid]);
    float og = sigm(gates[192 + tid]);
    float c = fg * cl[b * 64 + tid] + ig * gg;
    cl[b * 64 + tid] = c;
    float hnew = og * tanhf(c);
    hl[b * 64 + tid] = hnew;
    qv[tid] = hnew;
  }
  __syncthreads();

  // ---- attention (4 waves over nodes) ----
  const int beg = ptr[b], end = ptr[b + 1];
  const float q = qv[lane];
  float mw = -INFINITY;
  for (int n = beg + wid; n < end; n += 4) {
    float p = h[(size_t)n * 64 + lane] * q;
#pragma unroll
    for (int s = 32; s; s >>= 1) p += __shfl_xor(p, s);
    mw = fmaxf(mw, p);
  }
  if (lane == 0) redM[wid] = mw;
  __syncthreads();
  const float m = fmaxf(fmaxf(redM[0], redM[1]), fmaxf(redM[2], redM[3]));
  float ssum = 0.f, racc = 0.f;
  for (int n = beg + wid; n < end; n += 4) {
    float hv = h[(size_t)n * 64 + lane];
    float p = hv * q;
#pragma unroll
    for (int s = 32; s; s >>= 1) p += __shfl_xor(p, s);
    float a = expf(p - m);
    ssum += a;
    racc = fmaf(a, hv, racc);
  }
  if (lane == 0) redS[wid] = ssum;
  redR[wid][lane] = racc;
  __syncthreads();
  if (tid < 64) {
    float rs = redR[0][tid] + redR[1][tid] + redR[2][tid] + redR[3][tid];
    float sd = redS[0] + redS[1] + redS[2] + redS[3];
    float rr = (end > beg) ? rs / sd : 0.0f;
    qstar[b * 128 + tid] = qv[tid];
    qstar[b * 128 + 64 + tid] = rr;
    qs2[tid] = qv[tid];
    qs2[64 + tid] = rr;
  }
  if (!final_step) return;
  __syncthreads();

  // ---- regression head ----
  if (tid < 64) {
    float a = hb1[tid];
    for (int i = 0; i < 128; ++i) a = fmaf(qs2[i], hW1[i * 64 + tid], a);
    z1[tid] = fmaxf(a, 0.0f);
  }
  __syncthreads();
  if (tid < 32) {
    float a2 = hb2[tid];
    for (int i = 0; i < 64; ++i) a2 = fmaf(z1[i], hW2[i * 32 + tid], a2);
    z2[tid] = fmaxf(a2, 0.0f);
  }
  __syncthreads();
  if (tid < 64) {
    float p = (tid < 32) ? z2[tid] * hW3[tid] : 0.0f;
#pragma unroll
    for (int s = 32; s; s >>= 1) p += __shfl_xor(p, s);
    if (tid == 0) out[b] = p + hb3[0];
  }
}

extern "C" void kernel_launch(void* const* d_in, const int* in_sizes, int n_in,
                              void* d_out, int out_size, void* d_ws, size_t ws_size,
                              hipStream_t stream) {
  const float* x = (const float*)d_in[0];
  const int* eidx = (const int*)d_in[1];
  const float* ea = (const float*)d_in[2];
  const int* batch = (const int*)d_in[3];
  const float* Wenc = (const float*)d_in[4];
  const float* benc = (const float*)d_in[5];
  const float* eW1 = (const float*)d_in[6];
  const float* eb1 = (const float*)d_in[7];
  const float* eW2 = (const float*)d_in[8];
  const float* eb2 = (const float*)d_in[9];
  const float* root = (const float*)d_in[10];
  const float* cbias = (const float*)d_in[11];
  const float* gamma = (const float*)d_in[12];
  const float* beta = (const float*)d_in[13];
  const float* Wih = (const float*)d_in[14];
  const float* Whh = (const float*)d_in[15];
  const float* bih = (const float*)d_in[16];
  const float* bhh = (const float*)d_in[17];
  const float* hW1 = (const float*)d_in[18];
  const float* hb1 = (const float*)d_in[19];
  const float* hW2 = (const float*)d_in[20];
  const float* hb2 = (const float*)d_in[21];
  const float* hW3 = (const float*)d_in[22];
  const float* hb3 = (const float*)d_in[23];

  const int N = in_sizes[0] / ND;
  const int E = in_sizes[1] / 2;
  const int B = out_size;
  const int* srcp = eidx;
  const int* dstp = eidx + E;
  const int Etiles = (E + 63) / 64;

  // ---- workspace layout: [zeroed region | rest] ----
  float* ws = (float*)d_ws;
  float* deg = ws;                                     // N
  float* agg = deg + N;                                // N*64
  float* bnslab = agg + (size_t)N * 64;                // NL * NSLAB * 128
  float* qstar = bnslab + NL * NSLAB * 128;            // B*128
  float* hl = qstar + (size_t)B * 128;                 // B*64
  float* cl = hl + (size_t)B * 64;                     // B*64
  const long Z = (long)(cl + (size_t)B * 64 - ws);     // zeroed float count
  float* h = cl + (size_t)B * 64;                      // N*64
  float* hn = h + (size_t)N * 64;                      // N*64
  _Float16* w2P = (_Float16*)(hn + (size_t)N * 64);    // 3 * 65*8*64*8 f16
  float* WihT = (float*)(w2P + (size_t)3 * 65 * 8 * 64 * 8);  // 128*256
  float* WhhT = WihT + 128 * 256;                      // 64*256
  float* gbias = WhhT + 64 * 256;                      // 256
  int* dptr = (int*)(gbias + 256);                     // N+1
  int* cursor = dptr + N + 1;                          // N
  int* perm = cursor + N;                              // E
  int* srcP = perm + E;                                // E
  int* dstP = srcP + E;                                // E
  int* ptr = dstP + E;                                 // B+1

  const int nbEnc = (N * 64 + 255) / 256;
  const int nbDeg = (E + 255) / 256;
  const int nbPtr = (N + 255) / 256;
  const int nbPackW = (192 * 256 + 256 + 255) / 256;
  const int nbPack3 = 130 * NL;

  k_zero<<<512, 256, 0, stream>>>(ws, Z);
  k_setup<<<nbEnc + nbDeg + nbPtr + nbPackW + nbPack3, 256, 0, stream>>>(
      x, Wenc, benc, h, N, dstp, deg, E, batch, ptr, B,
      Wih, Whh, bih, bhh, WihT, WhhT, gbias, eW2, eb2, w2P,
      nbEnc, nbDeg, nbPtr, nbPackW);
  k_scan<<<1, 256, 0, stream>>>(deg, dptr, cursor, N);
  k_fill<<<(E + 255) / 256, 256, 0, stream>>>(dstp, srcp, cursor, perm, srcP, dstP, E);

  for (int l = 0; l < NL; ++l) {
    float* slab_l = bnslab + (size_t)l * NSLAB * 128;
    const _Float16* w2_l = w2P + (size_t)l * 65 * 8 * 64 * 8;
    k_msgagg<<<Etiles, 512, 0, stream>>>(ea, perm, eW1 + (size_t)l * ED * 64,
                                         eb1 + (size_t)l * 64, h, srcP, dstP, dptr,
                                         w2_l, agg, E);
    k_update<<<(N + 15) / 16, 256, 0, stream>>>(agg, deg, h, root + l * 64 * 64,
                                                cbias + l * 64, hn, slab_l, N);
    k_bn<<<(N * 64 + 255) / 256, 256, 0, stream>>>(hn, slab_l, gamma + l * 64,
                                                   beta + l * 64, h, agg, N);
  }

  for (int s = 0; s < NSTEPS; ++s) {
    k_s2s<<<B, 256, 0, stream>>>(h, ptr, qstar, hl, cl, WihT, WhhT, gbias,
                                 hW1, hb1, hW2, hb2, hW3, hb3, (float*)d_out,
                                 (s == NSTEPS - 1) ? 1 : 0);
  }
}